// Round 11
// baseline (296.496 us; speedup 1.0000x reference)
//
#include <hip/hip_runtime.h>
#include <hip/hip_cooperative_groups.h>

namespace cg = cooperative_groups;

// DiffuseLR v9: cooperative mega-kernel (GRID=256, co-residency-safe) with a
// checked fallback to the proven R9 7-kernel pipeline if the cooperative
// launch is rejected. Identical math on both paths:
//   gT[s][c] = sum_{e:src=s} wn_e*fc_w[c][dst_e] + dinv[s]^2*fc_w[c][s]
//   logits = x @ gT + b; out = softmax(logits)

#define N_NODES   20000
#define N_EDGES_C 640000
#define N_CLASSES 30
#define CPAD      32

// deg-hist geometry
#define HBLKS     32
#define HNODES    10000
#define HEDGES    (N_EDGES_C / HBLKS)     // 20000

// partition geometry
#define BN        64
#define NBUCKET   313
#define NPB       (NBUCKET * BN)          // 20032
#define NSLAB     256
#define SLAB_E    (N_EDGES_C / NSLAB)     // 2500
#define NSCAN     (NBUCKET * NSLAB)       // 80128
#define ECAP      2600

// gemm geometry
#define NCHUNK    64
#define NCHUNKS   313
#define XL_LD     130
#define GT_LD     68
#define GBX       128

#define GRID      256
#define TPB       512
#define DINVB     ((N_NODES + 255) / 256) // 79

union SMem {
    float hist[HNODES];                                            // 40000 B
    int   bc[NBUCKET];
    int   cur[NBUCKET];
    float tile[CPAD][65];
    struct { int lds[TPB]; int bb; } scan;
    struct { int2 srt[ECAP]; int hist[BN]; int rowst[BN]; int cur[BN]; } fold;
    struct { float xl[(NCHUNK / 2) * XL_LD]; float gt[CPAD * GT_LD]; } gemm;
    float lg[64 * 33];
};

__global__ __launch_bounds__(TPB, 2) void mega(
        const int* __restrict__ src, const int* __restrict__ dst,
        const float* __restrict__ ew, const float* __restrict__ x,
        const float* __restrict__ fc_w, const float* __restrict__ fc_b,
        float* __restrict__ out,
        float* __restrict__ degp,          // aliases part (time-disjoint)
        int2* __restrict__ erec,
        float* __restrict__ dinv, int* __restrict__ cnt, int* __restrict__ off,
        int* __restrict__ btot, float* __restrict__ fc_wT, float* __restrict__ gT) {
    cg::grid_group grid = cg::this_grid();
    __shared__ SMem sm;
    int t = threadIdx.x;
    float* part = degp;   // degp dead after P2; part written in P6

    // ---- P1: deg hist (64 units) + bucket counts (256) + fcT tiles (313) ----
    for (int u = blockIdx.x; u < 2 * HBLKS + NSLAB + NBUCKET; u += GRID) {
        if (u < 2 * HBLKS) {
            int eb = u >> 1, half = u & 1;
            int nbase = half * HNODES;
            for (int i = t; i < HNODES; i += TPB) sm.hist[i] = 0.f;
            __syncthreads();
            const int4* d4 = (const int4*)(dst + eb * HEDGES);
            const float4* w4 = (const float4*)(ew + eb * HEDGES);
            for (int i = t; i < HEDGES / 4; i += TPB) {
                int4 dv = d4[i]; float4 wv = w4[i];
                unsigned r;
                r = (unsigned)(dv.x - nbase); if (r < HNODES) atomicAdd(&sm.hist[r], wv.x);
                r = (unsigned)(dv.y - nbase); if (r < HNODES) atomicAdd(&sm.hist[r], wv.y);
                r = (unsigned)(dv.z - nbase); if (r < HNODES) atomicAdd(&sm.hist[r], wv.z);
                r = (unsigned)(dv.w - nbase); if (r < HNODES) atomicAdd(&sm.hist[r], wv.w);
            }
            __syncthreads();
            float* outp = degp + (size_t)u * HNODES;
            for (int i = t; i < HNODES; i += TPB) outp[i] = sm.hist[i];
        } else if (u < 2 * HBLKS + NSLAB) {
            int slab = u - 2 * HBLKS;
            for (int i = t; i < NBUCKET; i += TPB) sm.bc[i] = 0;
            __syncthreads();
            const int4* s4 = (const int4*)(src + slab * SLAB_E);
            for (int i = t; i < SLAB_E / 4; i += TPB) {
                int4 v = s4[i];
                atomicAdd(&sm.bc[v.x >> 6], 1);
                atomicAdd(&sm.bc[v.y >> 6], 1);
                atomicAdd(&sm.bc[v.z >> 6], 1);
                atomicAdd(&sm.bc[v.w >> 6], 1);
            }
            __syncthreads();
            for (int b = t; b < NBUCKET; b += TPB) cnt[b * NSLAB + slab] = sm.bc[b];
        } else {
            int n0 = (u - 2 * HBLKS - NSLAB) * 64;
            #pragma unroll
            for (int k = 0; k < 4; k++) {
                int idx = k * TPB + t; int c = idx >> 6, nn = idx & 63;
                int n = n0 + nn;
                sm.tile[c][nn] = (c < N_CLASSES && n < N_NODES) ? fc_w[c * N_NODES + n] : 0.f;
            }
            __syncthreads();
            #pragma unroll
            for (int k = 0; k < 4; k++) {
                int idx = k * TPB + t; int nn = idx >> 5, c = idx & 31;
                fc_wT[(size_t)(n0 + nn) * CPAD + c] = sm.tile[c][nn];
            }
        }
        __syncthreads();
    }
    grid.sync();

    // ---- P2: btot (313 units) + dinv (40 units) ----
    for (int u = blockIdx.x; u < NBUCKET + 40; u += GRID) {
        if (u < NBUCKET) {
            sm.scan.lds[t] = (t < NSLAB) ? cnt[u * NSLAB + t] : 0;
            __syncthreads();
            for (int o = TPB / 2; o > 0; o >>= 1) {
                if (t < o) sm.scan.lds[t] += sm.scan.lds[t + o];
                __syncthreads();
            }
            if (t == 0) btot[u] = sm.scan.lds[0];
        } else {
            int n = (u - NBUCKET) * TPB + t;
            if (n < N_NODES) {
                int half = n / HNODES, nn = n - half * HNODES;
                float s = 1.0f;
                for (int eb = 0; eb < HBLKS; eb++)
                    s += degp[(size_t)((eb << 1) | half) * HNODES + nn];
                dinv[n] = rsqrtf(s);
            }
        }
        __syncthreads();
    }
    grid.sync();

    // ---- P3: off[b][slab] ----
    for (int b = blockIdx.x; b < NBUCKET; b += GRID) {
        int s = 0;
        for (int i = t; i < b; i += TPB) s += btot[i];
        sm.scan.lds[t] = s;
        __syncthreads();
        for (int o = TPB / 2; o > 0; o >>= 1) {
            if (t < o) sm.scan.lds[t] += sm.scan.lds[t + o];
            __syncthreads();
        }
        if (t == 0) sm.scan.bb = sm.scan.lds[0];
        __syncthreads();
        int base = sm.scan.bb;
        int v = (t < NSLAB) ? cnt[b * NSLAB + t] : 0;
        if (t < NSLAB) sm.scan.lds[t] = v;
        __syncthreads();
        for (int o = 1; o < NSLAB; o <<= 1) {
            int u2 = (t < NSLAB && t >= o) ? sm.scan.lds[t - o] : 0;
            __syncthreads();
            if (t < NSLAB) sm.scan.lds[t] += u2;
            __syncthreads();
        }
        if (t < NSLAB) off[b * NSLAB + t] = base + sm.scan.lds[t] - v;
        if (b == NBUCKET - 1 && t == NSLAB - 1) off[NSCAN] = base + sm.scan.lds[t];
        __syncthreads();
    }
    grid.sync();

    // ---- P4: scatter ----
    for (int slab = blockIdx.x; slab < NSLAB; slab += GRID) {
        for (int b = t; b < NBUCKET; b += TPB) sm.cur[b] = off[b * NSLAB + slab];
        __syncthreads();
        int e0 = slab * SLAB_E;
        const int4* s4 = (const int4*)(src + e0);
        const int4* d4 = (const int4*)(dst + e0);
        const float4* w4 = (const float4*)(ew + e0);
        for (int i = t; i < SLAB_E / 4; i += TPB) {
            int4 sv = s4[i]; int4 dv = d4[i]; float4 wv = w4[i];
            int s, d, p; float wn;
            s = sv.x; d = dv.x; wn = dinv[s] * wv.x * dinv[d];
            p = atomicAdd(&sm.cur[s >> 6], 1);
            erec[p] = make_int2(((s & 63) << 15) | d, __float_as_int(wn));
            s = sv.y; d = dv.y; wn = dinv[s] * wv.y * dinv[d];
            p = atomicAdd(&sm.cur[s >> 6], 1);
            erec[p] = make_int2(((s & 63) << 15) | d, __float_as_int(wn));
            s = sv.z; d = dv.z; wn = dinv[s] * wv.z * dinv[d];
            p = atomicAdd(&sm.cur[s >> 6], 1);
            erec[p] = make_int2(((s & 63) << 15) | d, __float_as_int(wn));
            s = sv.w; d = dv.w; wn = dinv[s] * wv.w * dinv[d];
            p = atomicAdd(&sm.cur[s >> 6], 1);
            erec[p] = make_int2(((s & 63) << 15) | d, __float_as_int(wn));
        }
        __syncthreads();
    }
    grid.sync();

    // ---- P5: per-bucket LDS counting sort + register gather fold ----
    for (int bucket = blockIdx.x; bucket < NBUCKET; bucket += GRID) {
        int nlo = bucket * BN;
        int bstart = off[bucket * NSLAB];
        int bend   = off[(bucket + 1) * NSLAB];
        int len = min(bend - bstart, ECAP);
        if (t < BN) sm.fold.hist[t] = 0;
        __syncthreads();
        for (int i = t; i < len; i += TPB)
            atomicAdd(&sm.fold.hist[((unsigned)erec[bstart + i].x) >> 15], 1);
        __syncthreads();
        if (t < BN) {
            int h = sm.fold.hist[t];
            int v = h;
            #pragma unroll
            for (int o = 1; o < BN; o <<= 1) {
                int u2 = __shfl_up(v, o, 64);
                if (t >= o) v += u2;
            }
            sm.fold.rowst[t] = v - h;
            sm.fold.cur[t]   = v - h;
        }
        __syncthreads();
        for (int i = t; i < len; i += TPB) {
            int2 r = erec[bstart + i];
            int p = atomicAdd(&sm.fold.cur[((unsigned)r.x) >> 15], 1);
            sm.fold.srt[p] = r;
        }
        __syncthreads();
        int c = t & 31;
        int grp = t >> 5;
        for (int nn = grp; nn < BN; nn += 16) {
            int n = nlo + nn;
            if (n >= N_NODES) {
                if (n < NPB) gT[(size_t)n * CPAD + c] = 0.f;
                continue;
            }
            float di = dinv[n];
            float acc  = di * di * fc_wT[(size_t)n * CPAD + c];
            float acc2 = 0.f;
            int i = sm.fold.rowst[nn], re = i + sm.fold.hist[nn];
            for (; i + 1 < re; i += 2) {
                int2 r0 = sm.fold.srt[i], r1 = sm.fold.srt[i + 1];
                acc  += __int_as_float(r0.y) * fc_wT[(size_t)(r0.x & 0x7FFF) * CPAD + c];
                acc2 += __int_as_float(r1.y) * fc_wT[(size_t)(r1.x & 0x7FFF) * CPAD + c];
            }
            if (i < re) {
                int2 r0 = sm.fold.srt[i];
                acc += __int_as_float(r0.y) * fc_wT[(size_t)(r0.x & 0x7FFF) * CPAD + c];
            }
            gT[(size_t)n * CPAD + c] = acc + acc2;
        }
        __syncthreads();
    }
    grid.sync();

    // ---- P6: logits partials (256 units) ----
    for (int u = blockIdx.x; u < GBX * 2; u += GRID) {
        int bx = u & (GBX - 1), bh = u >> 7;
        int b0 = bh * 64;
        int wv = t >> 6, l = t & 63;
        float acc0 = 0.f, acc1 = 0.f, acc2 = 0.f, acc3 = 0.f;
        for (int j = 0; j < 3; j++) {
            int ch = bx + GBX * j;
            if (ch >= NCHUNKS) break;
            int n0 = ch * NCHUNK;
            for (int o = t; o < 64 * NCHUNK; o += TPB) {
                int b = o >> 6, n = o & (NCHUNK - 1);
                int gn = n0 + n;
                float v = (gn < N_NODES) ? x[(size_t)(b0 + b) * N_NODES + gn] : 0.f;
                sm.gemm.xl[(n >> 1) * XL_LD + b * 2 + (n & 1)] = v;
            }
            for (int o = t; o < NCHUNK * CPAD; o += TPB) {
                int n = o >> 5, cc = o & 31;
                sm.gemm.gt[cc * GT_LD + n] = gT[(size_t)n0 * CPAD + o];
            }
            __syncthreads();
            #pragma unroll
            for (int n4 = 0; n4 < NCHUNK / 4; n4++) {
                float2 xa = *(const float2*)&sm.gemm.xl[(2 * n4) * XL_LD + l * 2];
                float2 xb = *(const float2*)&sm.gemm.xl[(2 * n4 + 1) * XL_LD + l * 2];
                float4 ga = *(const float4*)&sm.gemm.gt[(wv)      * GT_LD + 4 * n4];
                float4 gb = *(const float4*)&sm.gemm.gt[(wv +  8) * GT_LD + 4 * n4];
                float4 gc = *(const float4*)&sm.gemm.gt[(wv + 16) * GT_LD + 4 * n4];
                float4 gd = *(const float4*)&sm.gemm.gt[(wv + 24) * GT_LD + 4 * n4];
                acc0 += xa.x * ga.x + xa.y * ga.y + xb.x * ga.z + xb.y * ga.w;
                acc1 += xa.x * gb.x + xa.y * gb.y + xb.x * gb.z + xb.y * gb.w;
                acc2 += xa.x * gc.x + xa.y * gc.y + xb.x * gc.z + xb.y * gc.w;
                acc3 += xa.x * gd.x + xa.y * gd.y + xb.x * gd.z + xb.y * gd.w;
            }
            __syncthreads();
        }
        size_t pb = (size_t)(bx * 2 + bh) * CPAD * 64;
        part[pb + (size_t)(wv)      * 64 + l] = acc0;
        part[pb + (size_t)(wv +  8) * 64 + l] = acc1;
        part[pb + (size_t)(wv + 16) * 64 + l] = acc2;
        part[pb + (size_t)(wv + 24) * 64 + l] = acc3;
        __syncthreads();
    }
    grid.sync();

    // ---- P7: final reduce + bias + softmax (2 units) ----
    for (int u = blockIdx.x; u < 2; u += GRID) {
        int bh = u;
        int l = t & 63;
        int cq = t >> 6;   // 0..7
        float s0 = 0.f, s1 = 0.f, s2 = 0.f, s3 = 0.f;
        for (int bx = 0; bx < GBX; bx++) {
            const float* p = part + (size_t)(bx * 2 + bh) * CPAD * 64;
            s0 += p[(cq)      * 64 + l];
            s1 += p[(cq +  8) * 64 + l];
            s2 += p[(cq + 16) * 64 + l];
            s3 += p[(cq + 24) * 64 + l];
        }
        sm.lg[l * 33 + cq]      = s0 + ((cq      < N_CLASSES) ? fc_b[cq]      : 0.f);
        sm.lg[l * 33 + cq + 8]  = s1 + ((cq + 8  < N_CLASSES) ? fc_b[cq + 8]  : 0.f);
        sm.lg[l * 33 + cq + 16] = s2 + ((cq + 16 < N_CLASSES) ? fc_b[cq + 16] : 0.f);
        sm.lg[l * 33 + cq + 24] = s3 + ((cq + 24 < N_CLASSES) ? fc_b[cq + 24] : 0.f);
        __syncthreads();
        if (t < 64) {
            int b = bh * 64 + t;
            float v[N_CLASSES], m = -1e30f;
            #pragma unroll
            for (int c = 0; c < N_CLASSES; c++) { v[c] = sm.lg[t * 33 + c]; m = fmaxf(m, v[c]); }
            float s = 0.f;
            #pragma unroll
            for (int c = 0; c < N_CLASSES; c++) { v[c] = __expf(v[c] - m); s += v[c]; }
            float inv = 1.0f / s;
            #pragma unroll
            for (int c = 0; c < N_CLASSES; c++) out[b * N_CLASSES + c] = v[c] * inv;
        }
        __syncthreads();
    }
}

// ======================= fallback: proven R9 pipeline =======================

__global__ __launch_bounds__(256) void k1_hists(const int* __restrict__ src,
        const int* __restrict__ dst, const float* __restrict__ w,
        float* __restrict__ degp, int* __restrict__ cnt) {
    __shared__ float h[HNODES];
    int bid = blockIdx.x;
    if (bid < 2 * HBLKS) {
        int eb = bid >> 1, half = bid & 1;
        int nbase = half * HNODES;
        for (int i = threadIdx.x; i < HNODES; i += 256) h[i] = 0.f;
        __syncthreads();
        const int4* d4 = (const int4*)(dst + eb * HEDGES);
        const float4* w4 = (const float4*)(w + eb * HEDGES);
        for (int i = threadIdx.x; i < HEDGES / 4; i += 256) {
            int4 dv = d4[i]; float4 wv = w4[i];
            unsigned r;
            r = (unsigned)(dv.x - nbase); if (r < HNODES) atomicAdd(&h[r], wv.x);
            r = (unsigned)(dv.y - nbase); if (r < HNODES) atomicAdd(&h[r], wv.y);
            r = (unsigned)(dv.z - nbase); if (r < HNODES) atomicAdd(&h[r], wv.z);
            r = (unsigned)(dv.w - nbase); if (r < HNODES) atomicAdd(&h[r], wv.w);
        }
        __syncthreads();
        float* outp = degp + (size_t)bid * HNODES;
        for (int i = threadIdx.x; i < HNODES; i += 256) outp[i] = h[i];
    } else {
        int slab = bid - 2 * HBLKS;
        int* bc = (int*)h;
        for (int i = threadIdx.x; i < NBUCKET; i += 256) bc[i] = 0;
        __syncthreads();
        const int4* s4 = (const int4*)(src + slab * SLAB_E);
        for (int i = threadIdx.x; i < SLAB_E / 4; i += 256) {
            int4 v = s4[i];
            atomicAdd(&bc[v.x >> 6], 1);
            atomicAdd(&bc[v.y >> 6], 1);
            atomicAdd(&bc[v.z >> 6], 1);
            atomicAdd(&bc[v.w >> 6], 1);
        }
        __syncthreads();
        for (int b = threadIdx.x; b < NBUCKET; b += 256) cnt[b * NSLAB + slab] = bc[b];
    }
}

__global__ __launch_bounds__(256) void k2_prep(const int* __restrict__ cnt,
        int* __restrict__ btot, const float* __restrict__ fc_w,
        const float* __restrict__ degp, float* __restrict__ fc_wT,
        float* __restrict__ dinv) {
    int bid = blockIdx.x;
    int t = threadIdx.x;
    if (bid < NBUCKET) {
        __shared__ int lds[256];
        lds[t] = cnt[bid * NSLAB + t];
        __syncthreads();
        for (int o = 128; o > 0; o >>= 1) {
            if (t < o) lds[t] += lds[t + o];
            __syncthreads();
        }
        if (t == 0) btot[bid] = lds[0];
    } else if (bid < 2 * NBUCKET) {
        __shared__ float tile[CPAD][65];
        int n0 = (bid - NBUCKET) * 64;
        #pragma unroll
        for (int k = 0; k < 8; k++) {
            int c = k * 4 + (t >> 6), nn = t & 63;
            int n = n0 + nn;
            tile[c][nn] = (c < N_CLASSES && n < N_NODES) ? fc_w[c * N_NODES + n] : 0.f;
        }
        __syncthreads();
        #pragma unroll
        for (int k = 0; k < 8; k++) {
            int idx = k * 256 + t;
            int nn = idx >> 5, c = idx & 31;
            fc_wT[(size_t)(n0 + nn) * CPAD + c] = tile[c][nn];
        }
    } else {
        int n = (bid - 2 * NBUCKET) * 256 + t;
        if (n < N_NODES) {
            int half = n / HNODES, nn = n - half * HNODES;
            float s = 1.0f;
            for (int eb = 0; eb < HBLKS; eb++)
                s += degp[(size_t)((eb << 1) | half) * HNODES + nn];
            dinv[n] = rsqrtf(s);
        }
    }
}

__global__ __launch_bounds__(256) void k3_off(const int* __restrict__ cnt,
        const int* __restrict__ btot, int* __restrict__ off) {
    __shared__ int lds[256];
    __shared__ int bb;
    int b = blockIdx.x, t = threadIdx.x;
    int s = 0;
    for (int i = t; i < b; i += 256) s += btot[i];
    lds[t] = s;
    __syncthreads();
    for (int o = 128; o > 0; o >>= 1) {
        if (t < o) lds[t] += lds[t + o];
        __syncthreads();
    }
    if (t == 0) bb = lds[0];
    __syncthreads();
    int base = bb;
    int v = cnt[b * NSLAB + t];
    lds[t] = v;
    __syncthreads();
    for (int o = 1; o < 256; o <<= 1) {
        int u = (t >= o) ? lds[t - o] : 0;
        __syncthreads();
        lds[t] += u;
        __syncthreads();
    }
    off[b * NSLAB + t] = base + lds[t] - v;
    if (b == NBUCKET - 1 && t == 255) off[NSCAN] = base + lds[t];
}

__global__ __launch_bounds__(512) void k4_scatter(const int* __restrict__ src,
        const int* __restrict__ dst, const float* __restrict__ w,
        const float* __restrict__ dinv, const int* __restrict__ off,
        int2* __restrict__ erec) {
    __shared__ int cur[NBUCKET];
    int slab = blockIdx.x;
    for (int b = threadIdx.x; b < NBUCKET; b += 512) cur[b] = off[b * NSLAB + slab];
    __syncthreads();
    int e0 = slab * SLAB_E;
    const int4* s4 = (const int4*)(src + e0);
    const int4* d4 = (const int4*)(dst + e0);
    const float4* w4 = (const float4*)(w + e0);
    for (int i = threadIdx.x; i < SLAB_E / 4; i += 512) {
        int4 sv = s4[i]; int4 dv = d4[i]; float4 wv = w4[i];
        int s, d, p; float wn;
        s = sv.x; d = dv.x; wn = dinv[s] * wv.x * dinv[d];
        p = atomicAdd(&cur[s >> 6], 1);
        erec[p] = make_int2(((s & 63) << 15) | d, __float_as_int(wn));
        s = sv.y; d = dv.y; wn = dinv[s] * wv.y * dinv[d];
        p = atomicAdd(&cur[s >> 6], 1);
        erec[p] = make_int2(((s & 63) << 15) | d, __float_as_int(wn));
        s = sv.z; d = dv.z; wn = dinv[s] * wv.z * dinv[d];
        p = atomicAdd(&cur[s >> 6], 1);
        erec[p] = make_int2(((s & 63) << 15) | d, __float_as_int(wn));
        s = sv.w; d = dv.w; wn = dinv[s] * wv.w * dinv[d];
        p = atomicAdd(&cur[s >> 6], 1);
        erec[p] = make_int2(((s & 63) << 15) | d, __float_as_int(wn));
    }
}

__global__ __launch_bounds__(512) void k5_fold(const int2* __restrict__ erec,
        const int* __restrict__ off, const float* __restrict__ dinv,
        const float* __restrict__ fc_wT, float* __restrict__ gT) {
    __shared__ int2 srt[ECAP];
    __shared__ int hist[BN];
    __shared__ int rowst[BN];
    __shared__ int cur[BN];
    int bucket = blockIdx.x;
    int nlo = bucket * BN;
    int bstart = off[bucket * NSLAB];
    int bend   = off[(bucket + 1) * NSLAB];
    int len = min(bend - bstart, ECAP);
    if (threadIdx.x < BN) hist[threadIdx.x] = 0;
    __syncthreads();
    for (int i = threadIdx.x; i < len; i += 512)
        atomicAdd(&hist[((unsigned)erec[bstart + i].x) >> 15], 1);
    __syncthreads();
    if (threadIdx.x < BN) {
        int h = hist[threadIdx.x];
        int v = h;
        #pragma unroll
        for (int o = 1; o < BN; o <<= 1) {
            int u = __shfl_up(v, o, 64);
            if (threadIdx.x >= o) v += u;
        }
        rowst[threadIdx.x] = v - h;
        cur[threadIdx.x]   = v - h;
    }
    __syncthreads();
    for (int i = threadIdx.x; i < len; i += 512) {
        int2 r = erec[bstart + i];
        int p = atomicAdd(&cur[((unsigned)r.x) >> 15], 1);
        srt[p] = r;
    }
    __syncthreads();
    int c = threadIdx.x & 31;
    int grp = threadIdx.x >> 5;
    for (int nn = grp; nn < BN; nn += 16) {
        int n = nlo + nn;
        if (n >= N_NODES) {
            if (n < NPB) gT[(size_t)n * CPAD + c] = 0.f;
            continue;
        }
        float di = dinv[n];
        float acc  = di * di * fc_wT[(size_t)n * CPAD + c];
        float acc2 = 0.f;
        int i = rowst[nn], re = i + hist[nn];
        for (; i + 1 < re; i += 2) {
            int2 r0 = srt[i], r1 = srt[i + 1];
            acc  += __int_as_float(r0.y) * fc_wT[(size_t)(r0.x & 0x7FFF) * CPAD + c];
            acc2 += __int_as_float(r1.y) * fc_wT[(size_t)(r1.x & 0x7FFF) * CPAD + c];
        }
        if (i < re) {
            int2 r0 = srt[i];
            acc += __int_as_float(r0.y) * fc_wT[(size_t)(r0.x & 0x7FFF) * CPAD + c];
        }
        gT[(size_t)n * CPAD + c] = acc + acc2;
    }
}

__global__ __launch_bounds__(512) void k6_gemm(const float* __restrict__ x,
        const float* __restrict__ gT, float* __restrict__ part) {
    __shared__ float xl[(NCHUNK / 2) * XL_LD];
    __shared__ float gt[CPAD * GT_LD];
    int bx = blockIdx.x, bh = blockIdx.y;
    int b0 = bh * 64;
    int wv = threadIdx.x >> 6, l = threadIdx.x & 63;
    float acc0 = 0.f, acc1 = 0.f, acc2 = 0.f, acc3 = 0.f;
    for (int j = 0; j < 3; j++) {
        int ch = bx + GBX * j;
        if (ch >= NCHUNKS) break;
        int n0 = ch * NCHUNK;
        for (int o = threadIdx.x; o < 64 * NCHUNK; o += 512) {
            int b = o >> 6, n = o & (NCHUNK - 1);
            int gn = n0 + n;
            float v = (gn < N_NODES) ? x[(size_t)(b0 + b) * N_NODES + gn] : 0.f;
            xl[(n >> 1) * XL_LD + b * 2 + (n & 1)] = v;
        }
        for (int o = threadIdx.x; o < NCHUNK * CPAD; o += 512) {
            int n = o >> 5, cc = o & 31;
            gt[cc * GT_LD + n] = gT[(size_t)n0 * CPAD + o];
        }
        __syncthreads();
        #pragma unroll
        for (int n4 = 0; n4 < NCHUNK / 4; n4++) {
            float2 xa = *(const float2*)&xl[(2 * n4) * XL_LD + l * 2];
            float2 xb = *(const float2*)&xl[(2 * n4 + 1) * XL_LD + l * 2];
            float4 ga = *(const float4*)&gt[(wv)      * GT_LD + 4 * n4];
            float4 gb = *(const float4*)&gt[(wv +  8) * GT_LD + 4 * n4];
            float4 gc = *(const float4*)&gt[(wv + 16) * GT_LD + 4 * n4];
            float4 gd = *(const float4*)&gt[(wv + 24) * GT_LD + 4 * n4];
            acc0 += xa.x * ga.x + xa.y * ga.y + xb.x * ga.z + xb.y * ga.w;
            acc1 += xa.x * gb.x + xa.y * gb.y + xb.x * gb.z + xb.y * gb.w;
            acc2 += xa.x * gc.x + xa.y * gc.y + xb.x * gc.z + xb.y * gc.w;
            acc3 += xa.x * gd.x + xa.y * gd.y + xb.x * gd.z + xb.y * gd.w;
        }
        __syncthreads();
    }
    size_t pb = (size_t)(bx * 2 + bh) * CPAD * 64;
    part[pb + (size_t)(wv)      * 64 + l] = acc0;
    part[pb + (size_t)(wv +  8) * 64 + l] = acc1;
    part[pb + (size_t)(wv + 16) * 64 + l] = acc2;
    part[pb + (size_t)(wv + 24) * 64 + l] = acc3;
}

__global__ __launch_bounds__(1024) void k7_final(const float* __restrict__ part,
        const float* __restrict__ fc_b, float* __restrict__ out) {
    __shared__ float lg[64 * 33];
    int bh = blockIdx.x;
    int l = threadIdx.x & 63;
    int cq = threadIdx.x >> 6;
    float s0 = 0.f, s1 = 0.f;
    for (int bx = 0; bx < GBX; bx++) {
        const float* p = part + (size_t)(bx * 2 + bh) * CPAD * 64;
        s0 += p[cq * 64 + l];
        s1 += p[(cq + 16) * 64 + l];
    }
    lg[l * 33 + cq]      = s0 + ((cq < N_CLASSES) ? fc_b[cq] : 0.f);
    lg[l * 33 + cq + 16] = s1 + ((cq + 16 < N_CLASSES) ? fc_b[cq + 16] : 0.f);
    __syncthreads();
    if (threadIdx.x < 64) {
        int b = bh * 64 + threadIdx.x;
        float v[N_CLASSES], m = -1e30f;
        #pragma unroll
        for (int c = 0; c < N_CLASSES; c++) { v[c] = lg[threadIdx.x * 33 + c]; m = fmaxf(m, v[c]); }
        float s = 0.f;
        #pragma unroll
        for (int c = 0; c < N_CLASSES; c++) { v[c] = __expf(v[c] - m); s += v[c]; }
        float inv = 1.0f / s;
        #pragma unroll
        for (int c = 0; c < N_CLASSES; c++) out[b * N_CLASSES + c] = v[c] * inv;
    }
}

extern "C" void kernel_launch(void* const* d_in, const int* in_sizes, int n_in,
                              void* d_out, int out_size, void* d_ws, size_t ws_size,
                              hipStream_t stream) {
    const float* x          = (const float*)d_in[0];
    const int*   edge_index = (const int*)d_in[1];
    const float* ew         = (const float*)d_in[2];
    const float* fc_w       = (const float*)d_in[3];
    const float* fc_b       = (const float*)d_in[4];
    float* out = (float*)d_out;

    const int* src = edge_index;
    const int* dst = edge_index + N_EDGES_C;

    // ws layout (float slots), time-disjoint aliasing:
    //   A (1,280,000): degp [P1..P2] -> part [P6..P7]
    //   B (1,280,000): erec [P4..P5]
    float* A     = (float*)d_ws;
    float* Bp    = A + 1280000;
    float* dinv  = Bp + 1280000;                             // 20,000
    int*   cnt   = (int*)(dinv + N_NODES);                   // 80,128
    int*   off   = cnt + NSCAN;                              // 80,129 (pad 80,136)
    int*   btot  = off + 80136;                              // 313 (pad 320)
    float* fc_wT = (float*)(btot + 320);                     // 641,024
    float* gT    = fc_wT + (size_t)NPB * CPAD;               // 641,024

    int2* erec = (int2*)Bp;

    void* args[] = {
        (void*)&src, (void*)&dst, (void*)&ew, (void*)&x, (void*)&fc_w,
        (void*)&fc_b, (void*)&out, (void*)&A, (void*)&erec,
        (void*)&dinv, (void*)&cnt, (void*)&off, (void*)&btot,
        (void*)&fc_wT, (void*)&gT
    };
    hipError_t e = hipLaunchCooperativeKernel((void*)mega, dim3(GRID), dim3(TPB),
                                              args, 0, stream);
    if (e != hipSuccess) {
        (void)hipGetLastError();   // clear sticky error, run proven pipeline
        k1_hists<<<2 * HBLKS + NSLAB, 256, 0, stream>>>(src, dst, ew, A, cnt);
        k2_prep<<<2 * NBUCKET + DINVB, 256, 0, stream>>>(cnt, btot, fc_w, A,
                                                         fc_wT, dinv);
        k3_off<<<NBUCKET, 256, 0, stream>>>(cnt, btot, off);
        k4_scatter<<<NSLAB, 512, 0, stream>>>(src, dst, ew, dinv, off, erec);
        k5_fold<<<NBUCKET, 512, 0, stream>>>(erec, off, dinv, fc_wT, gT);
        k6_gemm<<<dim3(GBX, 2), 512, 0, stream>>>(x, gT, A);
        k7_final<<<2, 1024, 0, stream>>>(A, fc_b, out);
    }
}

// Round 12
// 99.481 us; speedup vs baseline: 2.9804x; 2.9804x over previous
//
#include <hip/hip_runtime.h>

// DiffuseLR v10: 6 plain kernels (coop mega abandoned — 3x slower at 22% occ).
//   fcT'[n][c] = dinv[n]*fc_w[c][n]
//   gT[s][c]   = dinv[s]*(sum_{e:src=s} w_e*fcT'[dst_e][c] + fcT'[s][c])
//   logits = x @ gT + b; out = softmax(logits)
// Buckets are fixed-capacity (ECAP) regions reserved via LDS-aggregated device
// atomics (80K total) -> no cnt/btot/off counting-sort machinery. Fold+GEMM
// fused per bucket: gT never touches global memory; x read exactly once.

#define N_NODES   20000
#define N_EDGES_C 640000
#define N_CLASSES 30
#define CPAD      32

// deg-hist geometry
#define HBLKS     32
#define HNODES    10000
#define HEDGES    (N_EDGES_C / HBLKS)     // 20000

// partition geometry
#define BN        64
#define NBUCKET   313                     // ceil(20000/64)
#define NSLAB     256
#define SLAB_E    (N_EDGES_C / NSLAB)     // 2500
#define ECAP      2600                    // per-bucket cap (mean 2048, sd ~45)

// fused fold+gemm geometry
#define XLD       129                     // xl[n][b] row stride (pad -> conflict-free)
#define GTLD      65                      // gt[c][n] row stride

// K1: blocks [0,64): weighted in-degree LDS histogram per (edge-slab, half);
//     block 64: init gcur[b] = b*ECAP.
__global__ __launch_bounds__(512) void k1_hist(const int* __restrict__ dst,
        const float* __restrict__ ew, float* __restrict__ degp,
        int* __restrict__ gcur) {
    __shared__ float h[HNODES];   // 40 KB
    int bid = blockIdx.x;
    int t = threadIdx.x;
    if (bid < 2 * HBLKS) {
        int eb = bid >> 1, half = bid & 1;
        int nbase = half * HNODES;
        for (int i = t; i < HNODES; i += 512) h[i] = 0.f;
        __syncthreads();
        const int4* d4 = (const int4*)(dst + eb * HEDGES);
        const float4* w4 = (const float4*)(ew + eb * HEDGES);
        for (int i = t; i < HEDGES / 4; i += 512) {
            int4 dv = d4[i]; float4 wv = w4[i];
            unsigned r;
            r = (unsigned)(dv.x - nbase); if (r < HNODES) atomicAdd(&h[r], wv.x);
            r = (unsigned)(dv.y - nbase); if (r < HNODES) atomicAdd(&h[r], wv.y);
            r = (unsigned)(dv.z - nbase); if (r < HNODES) atomicAdd(&h[r], wv.z);
            r = (unsigned)(dv.w - nbase); if (r < HNODES) atomicAdd(&h[r], wv.w);
        }
        __syncthreads();
        float* outp = degp + (size_t)bid * HNODES;
        for (int i = t; i < HNODES; i += 512) outp[i] = h[i];
    } else {
        if (t < NBUCKET) gcur[t] = t * ECAP;
    }
}

// K2: scatter edges into fixed-capacity buckets. Per 2500-edge slab: LDS
// histogram over 313 buckets, ONE device atomicAdd per (block,bucket) to
// reserve a range, then scatter {(s_local<<15)|d, w_raw}. Independent of K1's
// hist (only needs gcur init).
__global__ __launch_bounds__(512) void k2_scatter(const int* __restrict__ src,
        const int* __restrict__ dst, const float* __restrict__ ew,
        int* __restrict__ gcur, int2* __restrict__ erec) {
    __shared__ int ssrc[SLAB_E];      // 10 KB
    __shared__ int shist[NBUCKET];
    __shared__ int scur[NBUCKET];
    int slab = blockIdx.x;
    int t = threadIdx.x;
    int e0 = slab * SLAB_E;
    for (int i = t; i < NBUCKET; i += 512) shist[i] = 0;
    __syncthreads();
    for (int i = t; i < SLAB_E; i += 512) {
        int s = src[e0 + i];
        ssrc[i] = s;
        atomicAdd(&shist[s >> 6], 1);
    }
    __syncthreads();
    if (t < NBUCKET) scur[t] = atomicAdd(&gcur[t], shist[t]);   // range reserve
    __syncthreads();
    for (int i = t; i < SLAB_E; i += 512) {
        int s = ssrc[i];
        int d = dst[e0 + i];
        float wv = ew[e0 + i];
        int p = atomicAdd(&scur[s >> 6], 1);                     // LDS cursor
        erec[p] = make_int2(((s & 63) << 15) | d, __float_as_int(wv));
    }
}

// K3: per 64-node group: dinv (coalesced serial slab loop, threads 0..63) +
// fcT'[n][c] = dinv[n]*fc_w[c][n] (LDS-tiled transpose).
__global__ __launch_bounds__(512) void k3_prep(const float* __restrict__ degp,
        const float* __restrict__ fc_w, float* __restrict__ dinv,
        float* __restrict__ fcT) {
    __shared__ float tile[CPAD][65];
    __shared__ float sdinv[BN];
    int n0 = blockIdx.x * BN;
    int t = threadIdx.x;
    if (t < BN) {
        int n = n0 + t;
        float di = 0.f;
        if (n < N_NODES) {
            int half = n / HNODES, nn = n - half * HNODES;
            float s = 1.0f;   // self-loop weight
            for (int eb = 0; eb < HBLKS; eb++)
                s += degp[(size_t)((eb << 1) | half) * HNODES + nn];
            di = rsqrtf(s);
            dinv[n] = di;
        }
        sdinv[t] = di;
    }
    #pragma unroll
    for (int k = 0; k < 4; k++) {        // load 32c x 64n, coalesced per row
        int idx = k * 512 + t;
        int c = idx >> 6, nn = idx & 63;
        int n = n0 + nn;
        tile[c][nn] = (c < N_CLASSES && n < N_NODES) ? fc_w[c * N_NODES + n] : 0.f;
    }
    __syncthreads();
    #pragma unroll
    for (int k = 0; k < 4; k++) {        // write fcT' = dinv*tile, coalesced
        int idx = k * 512 + t;
        int nn = idx >> 5, c = idx & 31;
        fcT[(size_t)(n0 + nn) * CPAD + c] = sdinv[nn] * tile[c][nn];
    }
}

// K4: fused fold+GEMM per bucket. Phase 1: LDS counting sort by node + register
// gather (as proven in R6-R9). Phase 2: gT tile stays in LDS; stage x chunk and
// compute logits partials for all 128 batches.
__global__ __launch_bounds__(512) void k4_foldgemm(const int2* __restrict__ erec,
        const int* __restrict__ gcur, const float* __restrict__ dinv,
        const float* __restrict__ fcT, const float* __restrict__ x,
        float* __restrict__ part) {
    __shared__ union {
        struct { int2 srt[ECAP]; int hist[BN]; int rowst[BN]; int cur[BN]; } f; // 21568 B
        struct { float xl[BN * XLD]; float gt[CPAD * GTLD]; } g;                // 41344 B
    } sm;
    float* gt = sm.g.gt;   // disjoint from f (offset 33024 > 21568): safe during fold
    int bucket = blockIdx.x;
    int t = threadIdx.x;
    int nlo = bucket * BN;
    int bstart = bucket * ECAP;
    int len = min(gcur[bucket] - bstart, ECAP);

    // ---- fold: counting sort by node ----
    if (t < BN) sm.f.hist[t] = 0;
    __syncthreads();
    for (int i = t; i < len; i += 512)
        atomicAdd(&sm.f.hist[((unsigned)erec[bstart + i].x) >> 15], 1);
    __syncthreads();
    if (t < BN) {
        int h = sm.f.hist[t];
        int v = h;
        #pragma unroll
        for (int o = 1; o < BN; o <<= 1) {
            int u = __shfl_up(v, o, 64);
            if (t >= o) v += u;
        }
        sm.f.rowst[t] = v - h;
        sm.f.cur[t]   = v - h;
    }
    __syncthreads();
    for (int i = t; i < len; i += 512) {
        int2 r = erec[bstart + i];
        int p = atomicAdd(&sm.f.cur[((unsigned)r.x) >> 15], 1);
        sm.f.srt[p] = r;
    }
    __syncthreads();

    // ---- fold: register gather, write gT tile to LDS (gt !overlap f) ----
    int c = t & 31;
    int grp = t >> 5;
    for (int nn = grp; nn < BN; nn += 16) {
        int n = nlo + nn;
        if (n >= N_NODES) { gt[c * GTLD + nn] = 0.f; continue; }
        float acc  = fcT[(size_t)n * CPAD + c];   // self-loop (pre-scaled)
        float acc2 = 0.f;
        int i = sm.f.rowst[nn], re = i + sm.f.hist[nn];
        for (; i + 1 < re; i += 2) {
            int2 r0 = sm.f.srt[i], r1 = sm.f.srt[i + 1];       // LDS broadcast
            acc  += __int_as_float(r0.y) * fcT[(size_t)(r0.x & 0x7FFF) * CPAD + c];
            acc2 += __int_as_float(r1.y) * fcT[(size_t)(r1.x & 0x7FFF) * CPAD + c];
        }
        if (i < re) {
            int2 r0 = sm.f.srt[i];
            acc += __int_as_float(r0.y) * fcT[(size_t)(r0.x & 0x7FFF) * CPAD + c];
        }
        gt[c * GTLD + nn] = dinv[n] * (acc + acc2);
    }
    __syncthreads();   // gt complete; f region dead

    // ---- gemm: stage x[128][64-chunk] transposed to xl[n][b] ----
    for (int o = t; o < 128 * BN; o += 512) {
        int b = o >> 6, n = o & 63;
        int gn = nlo + n;
        float v = (gn < N_NODES) ? x[(size_t)b * N_NODES + gn] : 0.f;
        sm.g.xl[n * XLD + b] = v;   // banks (n*129+b)%32 = (n+b)%32: conflict-free
    }
    __syncthreads();

    int wv = t >> 6, l = t & 63;   // wave = class group, lane = batch
    float a00 = 0.f, a01 = 0.f, a10 = 0.f, a11 = 0.f;
    float a20 = 0.f, a21 = 0.f, a30 = 0.f, a31 = 0.f;
    #pragma unroll 8
    for (int n = 0; n < BN; n++) {
        float x0 = sm.g.xl[n * XLD + l];
        float x1 = sm.g.xl[n * XLD + 64 + l];
        float g0 = gt[(wv)      * GTLD + n];   // wave-uniform broadcast
        float g1 = gt[(wv +  8) * GTLD + n];
        float g2 = gt[(wv + 16) * GTLD + n];
        float g3 = gt[(wv + 24) * GTLD + n];
        a00 += x0 * g0; a01 += x1 * g0;
        a10 += x0 * g1; a11 += x1 * g1;
        a20 += x0 * g2; a21 += x1 * g2;
        a30 += x0 * g3; a31 += x1 * g3;
    }
    float* pb = part + (size_t)bucket * CPAD * 128;
    pb[(wv)      * 128 + l]      = a00;
    pb[(wv)      * 128 + 64 + l] = a01;
    pb[(wv +  8) * 128 + l]      = a10;
    pb[(wv +  8) * 128 + 64 + l] = a11;
    pb[(wv + 16) * 128 + l]      = a20;
    pb[(wv + 16) * 128 + 64 + l] = a21;
    pb[(wv + 24) * 128 + l]      = a30;
    pb[(wv + 24) * 128 + 64 + l] = a31;
}

// K5: chunk reduction: lpart[q][c][b] = sum_{ch=q mod 4} part[ch][c][b]
__global__ __launch_bounds__(128) void k5_lred(const float* __restrict__ part,
        float* __restrict__ lpart) {
    int c = blockIdx.x, q = blockIdx.y;
    int b = threadIdx.x;
    float s = 0.f;
    for (int ch = q; ch < NBUCKET; ch += 4)
        s += part[(size_t)ch * CPAD * 128 + c * 128 + b];
    lpart[(q * CPAD + c) * 128 + b] = s;
}

// K6: final sum + bias + softmax
__global__ void k6_smax(const float* __restrict__ lpart,
        const float* __restrict__ fc_b, float* __restrict__ out) {
    int b = threadIdx.x;
    float v[N_CLASSES], m = -1e30f;
    #pragma unroll
    for (int ccl = 0; ccl < N_CLASSES; ccl++) {
        float s = fc_b[ccl];
        #pragma unroll
        for (int q = 0; q < 4; q++) s += lpart[(q * CPAD + ccl) * 128 + b];
        v[ccl] = s; m = fmaxf(m, s);
    }
    float s = 0.f;
    #pragma unroll
    for (int ccl = 0; ccl < N_CLASSES; ccl++) { v[ccl] = __expf(v[ccl] - m); s += v[ccl]; }
    float inv = 1.0f / s;
    #pragma unroll
    for (int ccl = 0; ccl < N_CLASSES; ccl++) out[b * N_CLASSES + ccl] = v[ccl] * inv;
}

extern "C" void kernel_launch(void* const* d_in, const int* in_sizes, int n_in,
                              void* d_out, int out_size, void* d_ws, size_t ws_size,
                              hipStream_t stream) {
    const float* x          = (const float*)d_in[0];
    const int*   edge_index = (const int*)d_in[1];
    const float* ew         = (const float*)d_in[2];
    const float* fc_w       = (const float*)d_in[3];
    const float* fc_b       = (const float*)d_in[4];
    float* out = (float*)d_out;

    const int* src = edge_index;
    const int* dst = edge_index + N_EDGES_C;

    // ws layout (float slots), time-disjoint aliasing:
    //   A (1,282,048): degp [K1..K3] (640,000) -> part [K4..K5] (1,282,048)
    float* A     = (float*)d_ws;                             // 1,282,048
    int2*  erec  = (int2*)(A + 1282048);                     // 813,800 int2
    float* dinv  = (float*)(erec + (size_t)NBUCKET * ECAP);  // 20,000
    int*   gcur  = (int*)(dinv + N_NODES);                   // 320
    float* fcT   = (float*)(gcur + 320);                     // 641,024
    float* lpart = fcT + (size_t)NBUCKET * BN * CPAD;        // 16,384

    float* degp = A;
    float* part = A;

    k1_hist<<<2 * HBLKS + 1, 512, 0, stream>>>(dst, ew, degp, gcur);
    k2_scatter<<<NSLAB, 512, 0, stream>>>(src, dst, ew, gcur, erec);
    k3_prep<<<NBUCKET, 512, 0, stream>>>(degp, fc_w, dinv, fcT);
    k4_foldgemm<<<NBUCKET, 512, 0, stream>>>(erec, gcur, dinv, fcT, x, part);
    k5_lred<<<dim3(CPAD, 4), 128, 0, stream>>>(part, lpart);
    k6_smax<<<1, 128, 0, stream>>>(lpart, fc_b, out);
}